// Round 1
// 221.444 us; speedup vs baseline: 1.0287x; 1.0287x over previous
//
#include <hip/hip_runtime.h>

#define B 4
#define M 8192
#define NSTY 8192
#define KNB 8
#define F 288
#define NT (M + NSTY)   // 16384
#define BM (B * M)      // 32768
#define SEGL (M * F)    // 2359296 elements per convert segment

typedef __attribute__((ext_vector_type(8))) short short8;
typedef __attribute__((ext_vector_type(4))) float floatx4;
typedef __attribute__((ext_vector_type(2))) float floatx2;

__device__ __forceinline__ float u2f(unsigned int u) {
    union { unsigned int u; float f; } c; c.u = u; return c.f;
}
__device__ __forceinline__ unsigned short f2b(float x) {
    union { float f; unsigned int u; } c; c.f = x;
    unsigned int r = c.u + 0x7FFFu + ((c.u >> 16) & 1u);
    return (unsigned short)(r >> 16);
}
__device__ __forceinline__ floatx2 bpair(unsigned int p) {
    floatx2 r;
    r.x = u2f(p << 16);
    r.y = u2f(p & 0xFFFF0000u);
    return r;
}
__device__ __forceinline__ void gload_lds16(const void* g, void* l) {
    __builtin_amdgcn_global_load_lds(
        (const __attribute__((address_space(1))) unsigned int*)g,
        (__attribute__((address_space(3))) unsigned int*)l, 16, 0, 0);
}

// ---------------- merged prep (1024-thread blocks) ----------------
// Block order: [0,4) deg LDS-histogram (one block per batch, ZERO global atomics,
//              starts first so it overlaps the streaming convert),
//              [4, 4+2304) f32->bf16 convert (segment-linear),
//              [2308, 2470) pack W.
#define PREP_DEG_BLKS 4
#define PREP_CVT_BLKS 2304   // 8 segments x 288 blocks; 8192 elems/block
#define PREP_PKW_BLKS 162    // 2*F*F / 1024
__global__ __launch_bounds__(1024) void prep_kernel(
                            const int* __restrict__ idx_k1, const int* __restrict__ idx_k2,
                            int* __restrict__ deg,
                            const float* __restrict__ fc, const float* __restrict__ fs,
                            unsigned short* __restrict__ fb,
                            const float* __restrict__ W1, const float* __restrict__ W2,
                            unsigned short* __restrict__ Wp1, unsigned short* __restrict__ Wp2) {
    int blk = blockIdx.x;
    int tid = threadIdx.x;
    if (blk < PREP_DEG_BLKS) {
        // Full per-batch degree histogram in LDS; flush with plain stores.
        // deg_out(u) = count of u in cat(idx_k2, idx_k1 + M) for this batch.
        __shared__ int h[NT];   // 64 KB
        for (int i = tid; i < NT; i += 1024) h[i] = 0;
        __syncthreads();
        int b = blk;
        const int4* p2 = (const int4*)(idx_k2 + (size_t)b * M * KNB);
        const int4* p1 = (const int4*)(idx_k1 + (size_t)b * M * KNB);
        #pragma unroll 2
        for (int i = tid; i < (M * KNB) / 4; i += 1024) {
            int4 v = p2[i];
            atomicAdd(&h[v.x], 1); atomicAdd(&h[v.y], 1);
            atomicAdd(&h[v.z], 1); atomicAdd(&h[v.w], 1);
        }
        #pragma unroll 2
        for (int i = tid; i < (M * KNB) / 4; i += 1024) {
            int4 v = p1[i];
            atomicAdd(&h[M + v.x], 1); atomicAdd(&h[M + v.y], 1);
            atomicAdd(&h[M + v.z], 1); atomicAdd(&h[M + v.w], 1);
        }
        __syncthreads();
        int4* dst = (int4*)(deg + (size_t)b * NT);
        const int4* hs = (const int4*)h;
        for (int i = tid; i < NT / 4; i += 1024) dst[i] = hs[i];
    } else if (blk < PREP_DEG_BLKS + PREP_CVT_BLKS) {
        // featb[b][0:M][F] <- feat_c[b]; featb[b][M:NT][F] <- feat_s[b]; pure linear copy.
        int cb = blk - PREP_DEG_BLKS;
        int seg = cb / 288;                   // const divisor -> magic mul
        int bis = cb - seg * 288;
        int b = seg >> 1, sty = seg & 1;
        unsigned int e = (unsigned int)bis * 8192u + (unsigned int)tid * 8u;
        const float* src = (sty ? fs : fc) + (size_t)b * SEGL + e;
        float4 x0 = *(const float4*)src;
        float4 x1 = *(const float4*)(src + 4);
        uint4 o;
        o.x = (unsigned int)f2b(x0.x) | ((unsigned int)f2b(x0.y) << 16);
        o.y = (unsigned int)f2b(x0.z) | ((unsigned int)f2b(x0.w) << 16);
        o.z = (unsigned int)f2b(x1.x) | ((unsigned int)f2b(x1.y) << 16);
        o.w = (unsigned int)f2b(x1.z) | ((unsigned int)f2b(x1.w) << 16);
        *(uint4*)(fb + (size_t)b * 2 * SEGL + (size_t)sty * SEGL + e) = o;
    } else {
        int t = (blk - PREP_DEG_BLKS - PREP_CVT_BLKS) * 1024 + tid;
        if (t >= 2 * F * F) return;
        int half = t >= F * F;
        int tt = t - half * F * F;
        int k = tt / F, n = tt - k * F;
        const float* W = half ? W2 : W1;
        unsigned short* Wp = half ? Wp2 : Wp1;
        Wp[((size_t)(k >> 3) * F + n) * 8 + (k & 7)] = f2b(W[tt]);
    }
}

// ---------------- gather kernels: 4 rows per wave, uint4 row loads over 36 lanes ----------------
// Prologue: 64 lanes = 4 rows x 16 edges, coalesced idx load + random deg load.
// XCD batch-affinity: xcd = blk&7, batch = xcd>>1.
template<int LAYER>
__global__ __launch_bounds__(256) void agg_kernel(
        const unsigned short* __restrict__ src_tbl,
        const int* __restrict__ idx_k1, const int* __restrict__ idx_k2,
        const int* __restrict__ deg, const float* __restrict__ b1,
        unsigned short* __restrict__ aggb) {
    const int NK = (LAYER == 1) ? 16 : 8;
    int tid = threadIdx.x, wid = tid >> 6, lane = tid & 63;
    int blk = blockIdx.x;
    int rx = blk & 7;
    int b = rx >> 1;
    int sub = (blk >> 3) * 2 + (rx & 1);      // [0, 512) 16-row group within batch
    int rbase = sub * 16 + wid * 4;           // this wave's 4 rows

    // prologue: lane = i*16 + e  (row i in [0,4), edge e in [0,16))
    int i4 = lane >> 4, e = lane & 15;
    size_t eb = ((size_t)b * M + rbase + i4) * KNB;
    int u;
    if (e < 8) u = idx_k2[eb + e];
    else       u = M + idx_k1[eb + e - 8];
    int dg = deg[b * NT + u];
    float w = rsqrtf((float)(dg < 1 ? 1 : dg));
    float wst = (e >= 8) ? w : 0.f;           // style-edge weight (LAYER 2 const term)

    float bb[8];
    if (LAYER == 2 && lane < 36) {
        float4 t0 = *(const float4*)(b1 + 8 * lane);
        float4 t1 = *(const float4*)(b1 + 8 * lane + 4);
        bb[0]=fmaxf(t0.x,0.f); bb[1]=fmaxf(t0.y,0.f); bb[2]=fmaxf(t0.z,0.f); bb[3]=fmaxf(t0.w,0.f);
        bb[4]=fmaxf(t1.x,0.f); bb[5]=fmaxf(t1.y,0.f); bb[6]=fmaxf(t1.z,0.f); bb[7]=fmaxf(t1.w,0.f);
    }

    const unsigned short* base = src_tbl + (size_t)b * (LAYER == 1 ? NT : M) * F;
    unsigned short* dbase = aggb + ((size_t)b * M + rbase) * F;

    #pragma unroll
    for (int i = 0; i < 4; ++i) {
        floatx2 acc[4];
        if (LAYER == 2) {
            float S = 0.f;
            #pragma unroll
            for (int j = 8; j < 16; ++j) S += __shfl(wst, i * 16 + j);
            #pragma unroll
            for (int j = 0; j < 4; ++j) { acc[j].x = bb[2*j] * S; acc[j].y = bb[2*j+1] * S; }
        } else {
            #pragma unroll
            for (int j = 0; j < 4; ++j) acc[j] = (floatx2){0.f, 0.f};
        }

        #pragma unroll
        for (int c = 0; c < NK / 8; ++c) {
            const unsigned short* sp[8];
            #pragma unroll
            for (int k = 0; k < 8; ++k) {
                int uk = __shfl(u, i * 16 + c * 8 + k);
                sp[k] = base + (size_t)uk * F + 8 * lane;
            }
            uint4 v[8];
            if (lane < 36) {
                #pragma unroll
                for (int k = 0; k < 8; ++k) v[k] = *(const uint4*)sp[k];
            }
            #pragma unroll
            for (int k = 0; k < 8; ++k) {
                float wk = __shfl(w, i * 16 + c * 8 + k);
                floatx2 wk2 = {wk, wk};
                acc[0] += wk2 * bpair(v[k].x);
                acc[1] += wk2 * bpair(v[k].y);
                acc[2] += wk2 * bpair(v[k].z);
                acc[3] += wk2 * bpair(v[k].w);
            }
        }

        if (lane < 36) {
            uint4 o;
            o.x = (unsigned int)f2b(acc[0].x*0.25f) | ((unsigned int)f2b(acc[0].y*0.25f) << 16);
            o.y = (unsigned int)f2b(acc[1].x*0.25f) | ((unsigned int)f2b(acc[1].y*0.25f) << 16);
            o.z = (unsigned int)f2b(acc[2].x*0.25f) | ((unsigned int)f2b(acc[2].y*0.25f) << 16);
            o.w = (unsigned int)f2b(acc[3].x*0.25f) | ((unsigned int)f2b(acc[3].y*0.25f) << 16);
            *(uint4*)(dbase + (size_t)i * F + 8 * lane) = o;
        }
    }
}

// ---------------- bf16 MFMA GEMM: C[64 rows x 288] = A @ Wp + bias, batch-swizzled ----------------
template<int RELU, int OUTBF16>
__global__ __launch_bounds__(256, 2) void gemm_kernel(
        const unsigned short* __restrict__ A,
        const unsigned short* __restrict__ Wp,
        const float* __restrict__ bias,
        void* __restrict__ Cout) {
    __shared__ __align__(16) unsigned short sA[64 * F];
    __shared__ __align__(16) unsigned short sB[2][4 * F * 8];
    int tid = threadIdx.x;
    int wid = tid >> 6, lane = tid & 63;
    int wm = wid & 1, wn = wid >> 1;
    int quad = lane >> 4, r16 = lane & 15;
    int blk = blockIdx.x;
    int rx = blk & 7;
    int b = rx >> 1;
    int sub = (blk >> 3) * 2 + (rx & 1);
    int row0 = b * M + sub * 64;

    const unsigned short* Ab = A + (size_t)row0 * F;
    #pragma unroll
    for (int rr = 0; rr < 9; ++rr)
        gload_lds16(Ab + (rr * 256 + tid) * 8, &sA[(rr * 256 + tid) * 8]);
    if (tid < 128) {
        #pragma unroll
        for (int rr = 0; rr < 9; ++rr)
            gload_lds16(Wp + (rr * 128 + tid) * 8, &sB[0][(rr * 128 + tid) * 8]);
    }

    floatx4 acc[9][2];
    #pragma unroll
    for (int ct = 0; ct < 9; ++ct)
        #pragma unroll
        for (int rt = 0; rt < 2; ++rt)
            acc[ct][rt] = (floatx4){0.f, 0.f, 0.f, 0.f};

    __syncthreads();

    for (int s = 0; s < 9; ++s) {
        if (s < 8 && tid < 128) {
            const unsigned short* src = Wp + (size_t)(s + 1) * 4 * F * 8;
            unsigned short* dstb = sB[(s + 1) & 1];
            #pragma unroll
            for (int rr = 0; rr < 9; ++rr)
                gload_lds16(src + (rr * 128 + tid) * 8, dstb + (rr * 128 + tid) * 8);
        }
        short8 a0 = *(const short8*)&sA[(wm * 32 + r16) * F + s * 32 + quad * 8];
        short8 a1 = *(const short8*)&sA[(wm * 32 + 16 + r16) * F + s * 32 + quad * 8];
        const unsigned short* bbp = &sB[s & 1][(quad * F + wn * 144 + r16) * 8];
        #pragma unroll
        for (int ct = 0; ct < 9; ++ct) {
            short8 bf = *(const short8*)(bbp + ct * 128);
            acc[ct][0] = __builtin_amdgcn_mfma_f32_16x16x32_bf16(a0, bf, acc[ct][0], 0, 0, 0);
            acc[ct][1] = __builtin_amdgcn_mfma_f32_16x16x32_bf16(a1, bf, acc[ct][1], 0, 0, 0);
        }
        __syncthreads();
    }

    #pragma unroll
    for (int ct = 0; ct < 9; ++ct) {
        int col = wn * 144 + ct * 16 + r16;
        float bc = bias[col];
        #pragma unroll
        for (int rt = 0; rt < 2; ++rt) {
            #pragma unroll
            for (int rg = 0; rg < 4; ++rg) {
                float v = acc[ct][rt][rg] + bc;
                if (RELU) v = fmaxf(v, 0.f);
                int grow = row0 + wm * 32 + quad * 4 + rt * 16 + rg;
                if (OUTBF16) ((unsigned short*)Cout)[(size_t)grow * F + col] = f2b(v);
                else         ((float*)Cout)[(size_t)grow * F + col] = v;
            }
        }
    }
}

extern "C" void kernel_launch(void* const* d_in, const int* in_sizes, int n_in,
                              void* d_out, int out_size, void* d_ws, size_t ws_size,
                              hipStream_t stream) {
    const float* feat_c = (const float*)d_in[0];
    const float* feat_s = (const float*)d_in[1];
    const int*   idx_k1 = (const int*)d_in[2];
    const int*   idx_k2 = (const int*)d_in[3];
    const float* W1     = (const float*)d_in[4];
    const float* b1     = (const float*)d_in[5];
    const float* W2     = (const float*)d_in[6];
    const float* b2     = (const float*)d_in[7];

    char* ws = (char*)d_ws;
    int*            deg  = (int*)ws;                                    // 256 KB
    unsigned short* Wp1  = (unsigned short*)(ws + 262144);
    unsigned short* Wp2  = (unsigned short*)(ws + 262144 + 165888);
    unsigned short* aggb = (unsigned short*)(ws + 262144 + 2 * 165888); // 18.9 MB

    unsigned short* featb = (unsigned short*)d_out;  // 37.75 MB bf16 table
    unsigned short* h1b   = (unsigned short*)d_out;  // first 18.9 MB, after agg1 done
    float*          out   = (float*)d_out;

    prep_kernel<<<PREP_DEG_BLKS + PREP_CVT_BLKS + PREP_PKW_BLKS, 1024, 0, stream>>>(
        idx_k1, idx_k2, deg, feat_c, feat_s, featb, W1, W2, Wp1, Wp2);

    agg_kernel<1><<<BM / 16, 256, 0, stream>>>(featb, idx_k1, idx_k2, deg, b1, aggb);
    gemm_kernel<1, 1><<<BM / 64, 256, 0, stream>>>(aggb, Wp1, b1, (void*)h1b);

    agg_kernel<2><<<BM / 16, 256, 0, stream>>>(h1b, idx_k1, idx_k2, deg, b1, aggb);
    gemm_kernel<0, 0><<<BM / 64, 256, 0, stream>>>(aggb, Wp2, b2, (void*)out);
}

// Round 2
// 219.851 us; speedup vs baseline: 1.0361x; 1.0072x over previous
//
#include <hip/hip_runtime.h>

#define B 4
#define M 8192
#define NSTY 8192
#define KNB 8
#define F 288
#define NT (M + NSTY)   // 16384
#define BM (B * M)      // 32768
#define SEGL (M * F)    // 2359296 elements per convert segment

typedef __attribute__((ext_vector_type(8))) short short8;
typedef __attribute__((ext_vector_type(4))) float floatx4;
typedef __attribute__((ext_vector_type(2))) float floatx2;

__device__ __forceinline__ float u2f(unsigned int u) {
    union { unsigned int u; float f; } c; c.u = u; return c.f;
}
__device__ __forceinline__ unsigned short f2b(float x) {
    union { float f; unsigned int u; } c; c.f = x;
    unsigned int r = c.u + 0x7FFFu + ((c.u >> 16) & 1u);
    return (unsigned short)(r >> 16);
}
__device__ __forceinline__ floatx2 bpair(unsigned int p) {
    floatx2 r;
    r.x = u2f(p << 16);
    r.y = u2f(p & 0xFFFF0000u);
    return r;
}
__device__ __forceinline__ void gload_lds16(const void* g, void* l) {
    __builtin_amdgcn_global_load_lds(
        (const __attribute__((address_space(1))) unsigned int*)g,
        (__attribute__((address_space(3))) unsigned int*)l, 16, 0, 0);
}

// ---------------- merged prep (1024-thread blocks) ----------------
// Block order: [0,4) deg LDS-histogram (one block per batch, zero global atomics),
//              [4, 4+576) f32->bf16 convert, 8 loads in flight per thread,
//              [580, 742) pack W.
#define PREP_DEG_BLKS 4
#define PREP_CVT_BLKS 576    // 8 segments x 72 blocks; 32768 elems/block
#define PREP_PKW_BLKS 162    // 2*F*F / 1024
__global__ __launch_bounds__(1024) void prep_kernel(
                            const int* __restrict__ idx_k1, const int* __restrict__ idx_k2,
                            int* __restrict__ deg,
                            const float* __restrict__ fc, const float* __restrict__ fs,
                            unsigned short* __restrict__ fb,
                            const float* __restrict__ W1, const float* __restrict__ W2,
                            unsigned short* __restrict__ Wp1, unsigned short* __restrict__ Wp2) {
    int blk = blockIdx.x;
    int tid = threadIdx.x;
    if (blk < PREP_DEG_BLKS) {
        // Full per-batch degree histogram in LDS; flush with plain stores.
        __shared__ int h[NT];   // 64 KB
        for (int i = tid; i < NT; i += 1024) h[i] = 0;
        __syncthreads();
        int b = blk;
        const int4* p2 = (const int4*)(idx_k2 + (size_t)b * M * KNB);
        const int4* p1 = (const int4*)(idx_k1 + (size_t)b * M * KNB);
        #pragma unroll 2
        for (int i = tid; i < (M * KNB) / 4; i += 1024) {
            int4 v = p2[i];
            atomicAdd(&h[v.x], 1); atomicAdd(&h[v.y], 1);
            atomicAdd(&h[v.z], 1); atomicAdd(&h[v.w], 1);
        }
        #pragma unroll 2
        for (int i = tid; i < (M * KNB) / 4; i += 1024) {
            int4 v = p1[i];
            atomicAdd(&h[M + v.x], 1); atomicAdd(&h[M + v.y], 1);
            atomicAdd(&h[M + v.z], 1); atomicAdd(&h[M + v.w], 1);
        }
        __syncthreads();
        int4* dst = (int4*)(deg + (size_t)b * NT);
        const int4* hs = (const int4*)h;
        for (int i = tid; i < NT / 4; i += 1024) dst[i] = hs[i];
    } else if (blk < PREP_DEG_BLKS + PREP_CVT_BLKS) {
        // featb[b][0:M][F] <- feat_c[b]; featb[b][M:NT][F] <- feat_s[b]; linear copy,
        // 8 independent float4 loads in flight per thread (MLP for HBM streaming).
        int cb = blk - PREP_DEG_BLKS;
        int seg = cb / 72;                    // const divisor -> magic mul
        int bis = cb - seg * 72;
        int b = seg >> 1, sty = seg & 1;
        const float* src0 = (sty ? fs : fc) + (size_t)b * SEGL;
        unsigned short* dst0 = fb + (size_t)b * 2 * SEGL + (size_t)sty * SEGL;
        unsigned int e0 = (unsigned int)bis * 32768u + (unsigned int)tid * 8u;
        float4 x[8];
        #pragma unroll
        for (int j = 0; j < 4; ++j) {
            const float* s = src0 + e0 + j * 8192u;
            x[2 * j]     = *(const float4*)s;
            x[2 * j + 1] = *(const float4*)(s + 4);
        }
        #pragma unroll
        for (int j = 0; j < 4; ++j) {
            uint4 o;
            o.x = (unsigned int)f2b(x[2*j].x)   | ((unsigned int)f2b(x[2*j].y)   << 16);
            o.y = (unsigned int)f2b(x[2*j].z)   | ((unsigned int)f2b(x[2*j].w)   << 16);
            o.z = (unsigned int)f2b(x[2*j+1].x) | ((unsigned int)f2b(x[2*j+1].y) << 16);
            o.w = (unsigned int)f2b(x[2*j+1].z) | ((unsigned int)f2b(x[2*j+1].w) << 16);
            *(uint4*)(dst0 + e0 + j * 8192u) = o;
        }
    } else {
        int t = (blk - PREP_DEG_BLKS - PREP_CVT_BLKS) * 1024 + tid;
        if (t >= 2 * F * F) return;
        int half = t >= F * F;
        int tt = t - half * F * F;
        int k = tt / F, n = tt - k * F;
        const float* W = half ? W2 : W1;
        unsigned short* Wp = half ? Wp2 : Wp1;
        Wp[((size_t)(k >> 3) * F + n) * 8 + (k & 7)] = f2b(W[tt]);
    }
}

// ---------------- gather kernels: 4 rows per wave, full-row load batch ----------------
// 32-bit byte offsets vs uniform base (table <38MB); uoff = u*576 premultiplied once.
// Prologue: 64 lanes = 4 rows x 16 edges, coalesced idx load + random deg load.
// XCD batch-affinity: xcd = blk&7, batch = xcd>>1.
template<int LAYER>
__global__ __launch_bounds__(256) void agg_kernel(
        const unsigned short* __restrict__ src_tbl,
        const int* __restrict__ idx_k1, const int* __restrict__ idx_k2,
        const int* __restrict__ deg, const float* __restrict__ b1,
        unsigned short* __restrict__ aggb) {
    const int NK = (LAYER == 1) ? 16 : 8;
    int tid = threadIdx.x, wid = tid >> 6, lane = tid & 63;
    int blk = blockIdx.x;
    int rx = blk & 7;
    int b = rx >> 1;
    int sub = (blk >> 3) * 2 + (rx & 1);      // [0, 512) 16-row group within batch
    int rbase = sub * 16 + wid * 4;           // this wave's 4 rows

    // prologue: lane = i*16 + e  (row i in [0,4), edge e in [0,16))
    int i4 = lane >> 4, e = lane & 15;
    size_t eb = ((size_t)b * M + rbase + i4) * KNB;
    int u;
    if (e < 8) u = idx_k2[eb + e];
    else       u = M + idx_k1[eb + e - 8];
    int dg = deg[b * NT + u];
    float w = rsqrtf((float)(dg < 1 ? 1 : dg));
    float wst = (e >= 8) ? w : 0.f;           // style-edge weight (LAYER 2 const term)
    unsigned int uoff = (unsigned int)u * (unsigned int)(F * 2);  // byte offset of row u

    float bb[8];
    if (LAYER == 2 && lane < 36) {
        float4 t0 = *(const float4*)(b1 + 8 * lane);
        float4 t1 = *(const float4*)(b1 + 8 * lane + 4);
        bb[0]=fmaxf(t0.x,0.f); bb[1]=fmaxf(t0.y,0.f); bb[2]=fmaxf(t0.z,0.f); bb[3]=fmaxf(t0.w,0.f);
        bb[4]=fmaxf(t1.x,0.f); bb[5]=fmaxf(t1.y,0.f); bb[6]=fmaxf(t1.z,0.f); bb[7]=fmaxf(t1.w,0.f);
    }

    const char* baseb = (const char*)(src_tbl + (size_t)b * (LAYER == 1 ? NT : M) * F);
    unsigned int lane16 = (unsigned int)lane * 16u;
    unsigned short* dbase = aggb + ((size_t)b * M + rbase) * F;

    #pragma unroll
    for (int i = 0; i < 4; ++i) {
        // issue the whole row's gather before any consumption: NK loads in flight
        unsigned int off[NK];
        #pragma unroll
        for (int k = 0; k < NK; ++k)
            off[k] = (unsigned int)__shfl((int)uoff, i * 16 + k) + lane16;
        uint4 v[NK];
        if (lane < 36) {
            #pragma unroll
            for (int k = 0; k < NK; ++k) v[k] = *(const uint4*)(baseb + off[k]);
        }

        floatx2 acc[4];
        if (LAYER == 2) {
            float S = 0.f;
            #pragma unroll
            for (int j = 8; j < 16; ++j) S += __shfl(wst, i * 16 + j);
            #pragma unroll
            for (int j = 0; j < 4; ++j) { acc[j].x = bb[2*j] * S; acc[j].y = bb[2*j+1] * S; }
        } else {
            #pragma unroll
            for (int j = 0; j < 4; ++j) acc[j] = (floatx2){0.f, 0.f};
        }

        #pragma unroll
        for (int k = 0; k < NK; ++k) {
            float wk = __shfl(w, i * 16 + k);
            floatx2 wk2 = {wk, wk};
            acc[0] += wk2 * bpair(v[k].x);
            acc[1] += wk2 * bpair(v[k].y);
            acc[2] += wk2 * bpair(v[k].z);
            acc[3] += wk2 * bpair(v[k].w);
        }

        if (lane < 36) {
            uint4 o;
            o.x = (unsigned int)f2b(acc[0].x*0.25f) | ((unsigned int)f2b(acc[0].y*0.25f) << 16);
            o.y = (unsigned int)f2b(acc[1].x*0.25f) | ((unsigned int)f2b(acc[1].y*0.25f) << 16);
            o.z = (unsigned int)f2b(acc[2].x*0.25f) | ((unsigned int)f2b(acc[2].y*0.25f) << 16);
            o.w = (unsigned int)f2b(acc[3].x*0.25f) | ((unsigned int)f2b(acc[3].y*0.25f) << 16);
            *(uint4*)(dbase + (size_t)i * F + 8 * lane) = o;
        }
    }
}

// ---------------- bf16 MFMA GEMM: C[64 rows x 288] = A @ Wp + bias, batch-swizzled ----------------
template<int RELU, int OUTBF16>
__global__ __launch_bounds__(256, 2) void gemm_kernel(
        const unsigned short* __restrict__ A,
        const unsigned short* __restrict__ Wp,
        const float* __restrict__ bias,
        void* __restrict__ Cout) {
    __shared__ __align__(16) unsigned short sA[64 * F];
    __shared__ __align__(16) unsigned short sB[2][4 * F * 8];
    int tid = threadIdx.x;
    int wid = tid >> 6, lane = tid & 63;
    int wm = wid & 1, wn = wid >> 1;
    int quad = lane >> 4, r16 = lane & 15;
    int blk = blockIdx.x;
    int rx = blk & 7;
    int b = rx >> 1;
    int sub = (blk >> 3) * 2 + (rx & 1);
    int row0 = b * M + sub * 64;

    const unsigned short* Ab = A + (size_t)row0 * F;
    #pragma unroll
    for (int rr = 0; rr < 9; ++rr)
        gload_lds16(Ab + (rr * 256 + tid) * 8, &sA[(rr * 256 + tid) * 8]);
    if (tid < 128) {
        #pragma unroll
        for (int rr = 0; rr < 9; ++rr)
            gload_lds16(Wp + (rr * 128 + tid) * 8, &sB[0][(rr * 128 + tid) * 8]);
    }

    floatx4 acc[9][2];
    #pragma unroll
    for (int ct = 0; ct < 9; ++ct)
        #pragma unroll
        for (int rt = 0; rt < 2; ++rt)
            acc[ct][rt] = (floatx4){0.f, 0.f, 0.f, 0.f};

    __syncthreads();

    for (int s = 0; s < 9; ++s) {
        if (s < 8 && tid < 128) {
            const unsigned short* src = Wp + (size_t)(s + 1) * 4 * F * 8;
            unsigned short* dstb = sB[(s + 1) & 1];
            #pragma unroll
            for (int rr = 0; rr < 9; ++rr)
                gload_lds16(src + (rr * 128 + tid) * 8, dstb + (rr * 128 + tid) * 8);
        }
        short8 a0 = *(const short8*)&sA[(wm * 32 + r16) * F + s * 32 + quad * 8];
        short8 a1 = *(const short8*)&sA[(wm * 32 + 16 + r16) * F + s * 32 + quad * 8];
        const unsigned short* bbp = &sB[s & 1][(quad * F + wn * 144 + r16) * 8];
        #pragma unroll
        for (int ct = 0; ct < 9; ++ct) {
            short8 bf = *(const short8*)(bbp + ct * 128);
            acc[ct][0] = __builtin_amdgcn_mfma_f32_16x16x32_bf16(a0, bf, acc[ct][0], 0, 0, 0);
            acc[ct][1] = __builtin_amdgcn_mfma_f32_16x16x32_bf16(a1, bf, acc[ct][1], 0, 0, 0);
        }
        __syncthreads();
    }

    #pragma unroll
    for (int ct = 0; ct < 9; ++ct) {
        int col = wn * 144 + ct * 16 + r16;
        float bc = bias[col];
        #pragma unroll
        for (int rt = 0; rt < 2; ++rt) {
            #pragma unroll
            for (int rg = 0; rg < 4; ++rg) {
                float v = acc[ct][rt][rg] + bc;
                if (RELU) v = fmaxf(v, 0.f);
                int grow = row0 + wm * 32 + quad * 4 + rt * 16 + rg;
                if (OUTBF16) ((unsigned short*)Cout)[(size_t)grow * F + col] = f2b(v);
                else         ((float*)Cout)[(size_t)grow * F + col] = v;
            }
        }
    }
}

extern "C" void kernel_launch(void* const* d_in, const int* in_sizes, int n_in,
                              void* d_out, int out_size, void* d_ws, size_t ws_size,
                              hipStream_t stream) {
    const float* feat_c = (const float*)d_in[0];
    const float* feat_s = (const float*)d_in[1];
    const int*   idx_k1 = (const int*)d_in[2];
    const int*   idx_k2 = (const int*)d_in[3];
    const float* W1     = (const float*)d_in[4];
    const float* b1     = (const float*)d_in[5];
    const float* W2     = (const float*)d_in[6];
    const float* b2     = (const float*)d_in[7];

    char* ws = (char*)d_ws;
    int*            deg  = (int*)ws;                                    // 256 KB
    unsigned short* Wp1  = (unsigned short*)(ws + 262144);
    unsigned short* Wp2  = (unsigned short*)(ws + 262144 + 165888);
    unsigned short* aggb = (unsigned short*)(ws + 262144 + 2 * 165888); // 18.9 MB

    unsigned short* featb = (unsigned short*)d_out;  // 37.75 MB bf16 table
    unsigned short* h1b   = (unsigned short*)d_out;  // first 18.9 MB, after agg1 done
    float*          out   = (float*)d_out;

    prep_kernel<<<PREP_DEG_BLKS + PREP_CVT_BLKS + PREP_PKW_BLKS, 1024, 0, stream>>>(
        idx_k1, idx_k2, deg, feat_c, feat_s, featb, W1, W2, Wp1, Wp2);

    agg_kernel<1><<<BM / 16, 256, 0, stream>>>(featb, idx_k1, idx_k2, deg, b1, aggb);
    gemm_kernel<1, 1><<<BM / 64, 256, 0, stream>>>(aggb, Wp1, b1, (void*)h1b);

    agg_kernel<2><<<BM / 16, 256, 0, stream>>>(h1b, idx_k1, idx_k2, deg, b1, aggb);
    gemm_kernel<0, 0><<<BM / 64, 256, 0, stream>>>(aggb, Wp2, b2, (void*)out);
}